// Round 1
// baseline (141.701 us; speedup 1.0000x reference)
//
#include <hip/hip_runtime.h>
#include <math.h>

// Problem constants (fixed by reference): N=32, RES=256, C=2, K=1024, T=1, EPS=1e-6
constexpr int   N_   = 32;
constexpr int   RES_ = 256;
constexpr int   K_   = 1024;
constexpr float EPS_ = 1e-6f;

// ---------------------------------------------------------------------------
// Bilinear sampling: one thread per (n,k). flow [N,RES,RES,2], kp [N,K,2] (x,y)
// Matches grid_sample(bilinear, padding_mode='zeros', align_corners=True) in
// pixel space: gather 4 clipped texels, zero out-of-bounds, blend.
// ---------------------------------------------------------------------------
__device__ __forceinline__ float2 gather_tex(const float* __restrict__ base, int xi, int yi) {
    bool valid = (xi >= 0) & (xi <= RES_ - 1) & (yi >= 0) & (yi <= RES_ - 1);
    int xc = min(max(xi, 0), RES_ - 1);
    int yc = min(max(yi, 0), RES_ - 1);
    float2 v = *reinterpret_cast<const float2*>(base + ((size_t)yc * RES_ + xc) * 2);
    float m = valid ? 1.0f : 0.0f;
    v.x *= m; v.y *= m;
    return v;
}

__global__ void __launch_bounds__(256) sample_kernel(const float* __restrict__ flow,
                                                     const float* __restrict__ kp,
                                                     float* __restrict__ out) {
    int idx = blockIdx.x * 256 + threadIdx.x;      // n*K + k
    if (idx >= N_ * K_) return;
    int n = idx >> 10;                              // K = 1024
    float2 p = reinterpret_cast<const float2*>(kp)[idx];
    float x0f = floorf(p.x), y0f = floorf(p.y);
    float wx = p.x - x0f,    wy = p.y - y0f;
    int x0 = (int)x0f, y0 = (int)y0f;
    const float* base = flow + (size_t)n * RES_ * RES_ * 2;
    float2 v00 = gather_tex(base, x0,     y0);
    float2 v10 = gather_tex(base, x0 + 1, y0);
    float2 v01 = gather_tex(base, x0,     y0 + 1);
    float2 v11 = gather_tex(base, x0 + 1, y0 + 1);
    float w00 = (1.0f - wx) * (1.0f - wy);
    float w10 = wx * (1.0f - wy);
    float w01 = (1.0f - wx) * wy;
    float w11 = wx * wy;
    float2 o;
    o.x = v00.x * w00 + v10.x * w10 + v01.x * w01 + v11.x * w11;
    o.y = v00.y * w00 + v10.y * w10 + v01.y * w01 + v11.y * w11;
    reinterpret_cast<float2*>(out)[idx] = o;
}

// ---------------------------------------------------------------------------
// Loss: loss[n,j] = 2*( log(sum_i exp(-dist(src[i],trg[j]))) + dist(src[j],trg[j]) )
//                   * vis[n,j] * wt[n,j]
// One block per (n, 256-wide j slab); src_c[n] staged in LDS (8 KB, broadcast
// reads -> conflict-free). Block-reduce loss contribution + vis count, one
// atomicAdd pair per block into accum[0..1].
// ---------------------------------------------------------------------------
__global__ void __launch_bounds__(256) loss_kernel(const float* __restrict__ src_c,
                                                   const float* __restrict__ trg_c,
                                                   const int* __restrict__ kp_vis,
                                                   const float* __restrict__ kp_wt,
                                                   float* __restrict__ accum) {
    __shared__ float2 s_src[K_];                    // 8 KB
    int n     = blockIdx.x >> 2;                    // 4 blocks per n
    int jbase = (blockIdx.x & 3) * 256;

    const float2* srcn = reinterpret_cast<const float2*>(src_c) + (size_t)n * K_;
    for (int i = threadIdx.x; i < K_; i += 256) s_src[i] = srcn[i];
    __syncthreads();

    int j  = jbase + threadIdx.x;
    int gj = n * K_ + j;
    float2 t = reinterpret_cast<const float2*>(trg_c)[gj];

    float s = 0.0f;
    #pragma unroll 8
    for (int i = 0; i < K_; ++i) {
        float dx = s_src[i].x - t.x + EPS_;
        float dy = s_src[i].y - t.y + EPS_;
        float d  = sqrtf(dx * dx + dy * dy);
        s += __expf(-d);                            // logits <= 0: no max trick needed
    }
    // diagonal term
    float dxj = s_src[j].x - t.x + EPS_;
    float dyj = s_src[j].y - t.y + EPS_;
    float djj = sqrtf(dxj * dxj + dyj * dyj);

    float visf    = kp_vis[gj] ? 1.0f : 0.0f;
    float contrib = 2.0f * (__logf(s) + djj) * visf * kp_wt[gj];
    float cnt     = visf;

    // wave(64) shuffle reduction, then cross-wave via LDS
    for (int off = 32; off > 0; off >>= 1) {
        contrib += __shfl_down(contrib, off);
        cnt     += __shfl_down(cnt, off);
    }
    __shared__ float s_v[4], s_c[4];
    int wid = threadIdx.x >> 6;
    if ((threadIdx.x & 63) == 0) { s_v[wid] = contrib; s_c[wid] = cnt; }
    __syncthreads();
    if (threadIdx.x == 0) {
        atomicAdd(&accum[0], s_v[0] + s_v[1] + s_v[2] + s_v[3]);
        atomicAdd(&accum[1], s_c[0] + s_c[1] + s_c[2] + s_c[3]);
    }
}

__global__ void finalize_kernel(const float* __restrict__ accum, float* __restrict__ out) {
    out[0] = accum[0] / accum[1];
}

// ---------------------------------------------------------------------------
extern "C" void kernel_launch(void* const* d_in, const int* in_sizes, int n_in,
                              void* d_out, int out_size, void* d_ws, size_t ws_size,
                              hipStream_t stream) {
    const float* src_flow = (const float*)d_in[0];
    const float* trg_flow = (const float*)d_in[1];
    const float* src_kp   = (const float*)d_in[2];
    const float* trg_kp   = (const float*)d_in[3];
    const int*   kp_vis   = (const int*)d_in[4];    // bool in reference -> int32 per harness
    const float* kp_wt    = (const float*)d_in[5];
    float* out = (float*)d_out;

    float* ws    = (float*)d_ws;
    float* accum = ws;                       // [0]=loss sum, [1]=vis count
    float* src_c = ws + 16;                  // [N,K,2] = 65536 floats
    float* trg_c = src_c + N_ * K_ * 2;      // [N,K,2]

    hipMemsetAsync(accum, 0, 2 * sizeof(float), stream);

    sample_kernel<<<(N_ * K_) / 256, 256, 0, stream>>>(src_flow, src_kp, src_c);
    sample_kernel<<<(N_ * K_) / 256, 256, 0, stream>>>(trg_flow, trg_kp, trg_c);
    loss_kernel<<<N_ * 4, 256, 0, stream>>>(src_c, trg_c, kp_vis, kp_wt, accum);
    finalize_kernel<<<1, 1, 0, stream>>>(accum, out);
}

// Round 2
// 111.329 us; speedup vs baseline: 1.2728x; 1.2728x over previous
//
#include <hip/hip_runtime.h>
#include <math.h>

// Problem constants (fixed by reference): N=32, RES=256, C=2, K=1024, T=1, EPS=1e-6
constexpr int   N_   = 32;
constexpr int   RES_ = 256;
constexpr int   K_   = 1024;
constexpr float EPS_ = 1e-6f;

constexpr int BLK_PER_N = 16;          // j-slabs of 64 per image
constexpr int NBLK      = N_ * BLK_PER_N;   // 512 blocks
constexpr int NTHR      = 512;         // 8 waves/block

// ---------------------------------------------------------------------------
// Bilinear sample of one keypoint from flow[n] (RES x RES x 2), zeros padding,
// align_corners=True in pixel space.
// ---------------------------------------------------------------------------
__device__ __forceinline__ float2 gather_tex(const float* __restrict__ base, int xi, int yi) {
    bool valid = (xi >= 0) & (xi <= RES_ - 1) & (yi >= 0) & (yi <= RES_ - 1);
    int xc = min(max(xi, 0), RES_ - 1);
    int yc = min(max(yi, 0), RES_ - 1);
    float2 v = *reinterpret_cast<const float2*>(base + ((size_t)yc * RES_ + xc) * 2);
    float m = valid ? 1.0f : 0.0f;
    v.x *= m; v.y *= m;
    return v;
}

__device__ __forceinline__ float2 sample_one(const float* __restrict__ base, float2 p) {
    float x0f = floorf(p.x), y0f = floorf(p.y);
    float wx = p.x - x0f,    wy = p.y - y0f;
    int x0 = (int)x0f, y0 = (int)y0f;
    float2 v00 = gather_tex(base, x0,     y0);
    float2 v10 = gather_tex(base, x0 + 1, y0);
    float2 v01 = gather_tex(base, x0,     y0 + 1);
    float2 v11 = gather_tex(base, x0 + 1, y0 + 1);
    float w00 = (1.0f - wx) * (1.0f - wy);
    float w10 = wx * (1.0f - wy);
    float w01 = (1.0f - wx) * wy;
    float w11 = wx * wy;
    float2 o;
    o.x = v00.x * w00 + v10.x * w10 + v01.x * w01 + v11.x * w11;
    o.y = v00.y * w00 + v10.y * w10 + v01.y * w01 + v11.y * w11;
    return o;
}

// ---------------------------------------------------------------------------
// Fused: sample src keypoints of image n into LDS, sample trg for this block's
// 64 j's, then loss[n,j] = 2*(log(sum_i exp(-dist_ij)) + dist_jj)*vis*wt.
// Wave w (of 8) handles i-chunk [w*128, w*128+128); lane l handles j=jbase+l.
// Inner loop: all 64 lanes read the SAME LDS address (broadcast, 0 conflicts).
// Per-block partial (loss, viscount) written to ws; no atomics, no memset.
// ---------------------------------------------------------------------------
__global__ void __launch_bounds__(NTHR) fused_loss_kernel(
        const float* __restrict__ src_flow, const float* __restrict__ trg_flow,
        const float* __restrict__ src_kp,   const float* __restrict__ trg_kp,
        const int*   __restrict__ kp_vis,   const float* __restrict__ kp_wt,
        float* __restrict__ partials) {
    __shared__ float2 s_src[K_];            // 8 KB
    __shared__ float  s_part[8][64];        // 2 KB

    const int blk   = blockIdx.x;
    const int n     = blk >> 4;             // 16 blocks per n
    const int jbase = (blk & 15) * 64;
    const int t     = threadIdx.x;
    const int wave  = t >> 6;
    const int lane  = t & 63;

    // Stage src_c[n][0..K) into LDS: 512 threads x 2 keypoints each.
    const float2* skp  = reinterpret_cast<const float2*>(src_kp) + (size_t)n * K_;
    const float* sbase = src_flow + (size_t)n * RES_ * RES_ * 2;
    #pragma unroll
    for (int k = t; k < K_; k += NTHR) s_src[k] = sample_one(sbase, skp[k]);

    // Sample trg for j = jbase + lane (redundant across the 8 waves; cheap).
    const float2* tkp  = reinterpret_cast<const float2*>(trg_kp) + (size_t)n * K_;
    const float* tbase = trg_flow + (size_t)n * RES_ * RES_ * 2;
    const int j  = jbase + lane;
    float2 tc = sample_one(tbase, tkp[j]);
    const float tx = tc.x - EPS_;           // d = s - t + EPS  ==  s - (t - EPS)
    const float ty = tc.y - EPS_;

    __syncthreads();

    float s = 0.0f;
    const int i0 = wave * (K_ / 8);         // 128 i's per wave
    #pragma unroll 4
    for (int k2 = 0; k2 < K_ / 8; ++k2) {
        float2 sc = s_src[i0 + k2];
        float dx = sc.x - tx;
        float dy = sc.y - ty;
        float d  = sqrtf(dx * dx + dy * dy);
        s += __expf(-d);
    }
    s_part[wave][lane] = s;
    __syncthreads();

    if (wave == 0) {
        float ssum = 0.0f;
        #pragma unroll
        for (int w = 0; w < 8; ++w) ssum += s_part[w][lane];
        float2 sj  = s_src[j];
        float dxj = sj.x - tx, dyj = sj.y - ty;
        float djj = sqrtf(dxj * dxj + dyj * dyj);
        const int gj = n * K_ + j;
        float visf = kp_vis[gj] ? 1.0f : 0.0f;
        float contrib = 2.0f * (__logf(ssum) + djj) * visf * kp_wt[gj];
        float cnt = visf;
        #pragma unroll
        for (int off = 32; off > 0; off >>= 1) {
            contrib += __shfl_down(contrib, off);
            cnt     += __shfl_down(cnt, off);
        }
        if (lane == 0) {
            partials[blk * 2]     = contrib;
            partials[blk * 2 + 1] = cnt;
        }
    }
}

// ---------------------------------------------------------------------------
// Sum 512 (loss, cnt) pairs, divide. One block.
// ---------------------------------------------------------------------------
__global__ void __launch_bounds__(256) finalize_kernel(const float* __restrict__ partials,
                                                       float* __restrict__ out) {
    const int t = threadIdx.x;
    float v = 0.0f, c = 0.0f;
    #pragma unroll
    for (int b = t; b < NBLK; b += 256) {
        v += partials[b * 2];
        c += partials[b * 2 + 1];
    }
    #pragma unroll
    for (int off = 32; off > 0; off >>= 1) {
        v += __shfl_down(v, off);
        c += __shfl_down(c, off);
    }
    __shared__ float s_v[4], s_c[4];
    int wid = t >> 6;
    if ((t & 63) == 0) { s_v[wid] = v; s_c[wid] = c; }
    __syncthreads();
    if (t == 0) {
        out[0] = (s_v[0] + s_v[1] + s_v[2] + s_v[3]) /
                 (s_c[0] + s_c[1] + s_c[2] + s_c[3]);
    }
}

// ---------------------------------------------------------------------------
extern "C" void kernel_launch(void* const* d_in, const int* in_sizes, int n_in,
                              void* d_out, int out_size, void* d_ws, size_t ws_size,
                              hipStream_t stream) {
    const float* src_flow = (const float*)d_in[0];
    const float* trg_flow = (const float*)d_in[1];
    const float* src_kp   = (const float*)d_in[2];
    const float* trg_kp   = (const float*)d_in[3];
    const int*   kp_vis   = (const int*)d_in[4];
    const float* kp_wt    = (const float*)d_in[5];
    float* out = (float*)d_out;

    float* partials = (float*)d_ws;          // [NBLK*2], fully overwritten each call

    fused_loss_kernel<<<NBLK, NTHR, 0, stream>>>(src_flow, trg_flow, src_kp, trg_kp,
                                                 kp_vis, kp_wt, partials);
    finalize_kernel<<<1, 256, 0, stream>>>(partials, out);
}

// Round 3
// 97.731 us; speedup vs baseline: 1.4499x; 1.1391x over previous
//
#include <hip/hip_runtime.h>
#include <math.h>

// Problem constants (fixed by reference): N=32, RES=256, C=2, K=1024, T=1, EPS=1e-6
constexpr int   N_   = 32;
constexpr int   RES_ = 256;
constexpr int   K_   = 1024;
constexpr float EPS_ = 1e-6f;
constexpr float LOG2E_ = 1.44269504088896340736f;   // scale coords by this
constexpr float LN2_   = 0.69314718055994530942f;

constexpr int BLK_PER_N = 16;               // j-slabs of 64 per image
constexpr int NBLK      = N_ * BLK_PER_N;   // 512 blocks
constexpr int NTHR      = 512;              // 8 waves/block

// ---------------------------------------------------------------------------
// Bilinear sample (grid_sample, zeros padding, align_corners=True, pixel coords)
// ---------------------------------------------------------------------------
__device__ __forceinline__ float2 gather_tex(const float* __restrict__ base, int xi, int yi) {
    bool valid = (xi >= 0) & (xi <= RES_ - 1) & (yi >= 0) & (yi <= RES_ - 1);
    int xc = min(max(xi, 0), RES_ - 1);
    int yc = min(max(yi, 0), RES_ - 1);
    float2 v = *reinterpret_cast<const float2*>(base + ((size_t)yc * RES_ + xc) * 2);
    float m = valid ? 1.0f : 0.0f;
    v.x *= m; v.y *= m;
    return v;
}

__device__ __forceinline__ float2 sample_one(const float* __restrict__ base, float2 p) {
    float x0f = floorf(p.x), y0f = floorf(p.y);
    float wx = p.x - x0f,    wy = p.y - y0f;
    int x0 = (int)x0f, y0 = (int)y0f;
    float2 v00 = gather_tex(base, x0,     y0);
    float2 v10 = gather_tex(base, x0 + 1, y0);
    float2 v01 = gather_tex(base, x0,     y0 + 1);
    float2 v11 = gather_tex(base, x0 + 1, y0 + 1);
    float w00 = (1.0f - wx) * (1.0f - wy);
    float w10 = wx * (1.0f - wy);
    float w01 = (1.0f - wx) * wy;
    float w11 = wx * wy;
    float2 o;
    o.x = v00.x * w00 + v10.x * w10 + v01.x * w01 + v11.x * w11;
    o.y = v00.y * w00 + v10.y * w10 + v01.y * w01 + v11.y * w11;
    return o;
}

// ---------------------------------------------------------------------------
// Fused kernel. All sampled coords pre-scaled by log2(e), so with
// r = sqrt(dx^2+dy^2) = log2(e)*dist:
//   exp(-dist)  == 2^(-r)              (v_exp_f32 with free -src modifier)
//   ln(sum)     == ln2 * log2(sum)     (v_log_f32)
//   dist_jj     == ln2 * r_jj
// contrib[j] = 2*ln2*(log2(sum_i 2^-r_ij) + r_jj) * vis * wt
// Wave w of 8 handles i-chunk [w*128, w*128+128); lane = j. LDS reads are
// wave-broadcast (all 64 lanes same address) -> conflict-free, ds_read_b128.
// ---------------------------------------------------------------------------
__global__ void __launch_bounds__(NTHR) fused_loss_kernel(
        const float* __restrict__ src_flow, const float* __restrict__ trg_flow,
        const float* __restrict__ src_kp,   const float* __restrict__ trg_kp,
        const int*   __restrict__ kp_vis,   const float* __restrict__ kp_wt,
        float* __restrict__ partials) {
    __shared__ __align__(16) float2 s_src[K_];   // 8 KB, log2e-scaled coords
    __shared__ float s_part[8][64];              // 2 KB

    const int blk   = blockIdx.x;
    const int n     = blk >> 4;                  // 16 blocks per n
    const int jbase = (blk & 15) * 64;
    const int t     = threadIdx.x;
    const int wave  = t >> 6;
    const int lane  = t & 63;

    // Stage log2e * src_c[n][0..K) into LDS: 512 threads x 2 keypoints each.
    const float2* skp  = reinterpret_cast<const float2*>(src_kp) + (size_t)n * K_;
    const float* sbase = src_flow + (size_t)n * RES_ * RES_ * 2;
    #pragma unroll
    for (int k = t; k < K_; k += NTHR) {
        float2 v = sample_one(sbase, skp[k]);
        v.x *= LOG2E_; v.y *= LOG2E_;
        s_src[k] = v;
    }

    // Sample trg for j = jbase + lane (redundant across 8 waves; cheap).
    const float2* tkp  = reinterpret_cast<const float2*>(trg_kp) + (size_t)n * K_;
    const float* tbase = trg_flow + (size_t)n * RES_ * RES_ * 2;
    const int j  = jbase + lane;
    float2 tc = sample_one(tbase, tkp[j]);
    // dx = log2e*(sx - tx + eps) = s_scaled.x - (log2e*tx - log2e*eps)
    const float tx = LOG2E_ * tc.x - LOG2E_ * EPS_;
    const float ty = LOG2E_ * tc.y - LOG2E_ * EPS_;

    __syncthreads();

    // 128 i's per wave, read as 64 float4 (2 points each), broadcast.
    const float4* s4 = reinterpret_cast<const float4*>(s_src) + wave * 64;
    float s0 = 0.0f, s1 = 0.0f;
    #pragma unroll 8
    for (int k2 = 0; k2 < 64; ++k2) {
        float4 p = s4[k2];
        float dx0 = p.x - tx, dy0 = p.y - ty;
        float dx1 = p.z - tx, dy1 = p.w - ty;
        float r0 = __builtin_amdgcn_sqrtf(dx0 * dx0 + dy0 * dy0);
        float r1 = __builtin_amdgcn_sqrtf(dx1 * dx1 + dy1 * dy1);
        s0 += __builtin_amdgcn_exp2f(-r0);
        s1 += __builtin_amdgcn_exp2f(-r1);
    }
    s_part[wave][lane] = s0 + s1;
    __syncthreads();

    if (wave == 0) {
        float ssum = 0.0f;
        #pragma unroll
        for (int w = 0; w < 8; ++w) ssum += s_part[w][lane];
        float2 sj = s_src[j];
        float dxj = sj.x - tx, dyj = sj.y - ty;
        float rjj = __builtin_amdgcn_sqrtf(dxj * dxj + dyj * dyj);
        const int gj = n * K_ + j;
        float visf = kp_vis[gj] ? 1.0f : 0.0f;
        float contrib = (2.0f * LN2_) * (__builtin_amdgcn_logf(ssum) + rjj)
                        * visf * kp_wt[gj];
        float cnt = visf;
        #pragma unroll
        for (int off = 32; off > 0; off >>= 1) {
            contrib += __shfl_down(contrib, off);
            cnt     += __shfl_down(cnt, off);
        }
        if (lane == 0) {
            partials[blk * 2]     = contrib;
            partials[blk * 2 + 1] = cnt;
        }
    }
}

// ---------------------------------------------------------------------------
// Sum 512 (loss, cnt) pairs, divide. One block.
// ---------------------------------------------------------------------------
__global__ void __launch_bounds__(256) finalize_kernel(const float* __restrict__ partials,
                                                       float* __restrict__ out) {
    const int t = threadIdx.x;
    float v = 0.0f, c = 0.0f;
    #pragma unroll
    for (int b = t; b < NBLK; b += 256) {
        v += partials[b * 2];
        c += partials[b * 2 + 1];
    }
    #pragma unroll
    for (int off = 32; off > 0; off >>= 1) {
        v += __shfl_down(v, off);
        c += __shfl_down(c, off);
    }
    __shared__ float s_v[4], s_c[4];
    int wid = t >> 6;
    if ((t & 63) == 0) { s_v[wid] = v; s_c[wid] = c; }
    __syncthreads();
    if (t == 0) {
        out[0] = (s_v[0] + s_v[1] + s_v[2] + s_v[3]) /
                 (s_c[0] + s_c[1] + s_c[2] + s_c[3]);
    }
}

// ---------------------------------------------------------------------------
extern "C" void kernel_launch(void* const* d_in, const int* in_sizes, int n_in,
                              void* d_out, int out_size, void* d_ws, size_t ws_size,
                              hipStream_t stream) {
    const float* src_flow = (const float*)d_in[0];
    const float* trg_flow = (const float*)d_in[1];
    const float* src_kp   = (const float*)d_in[2];
    const float* trg_kp   = (const float*)d_in[3];
    const int*   kp_vis   = (const int*)d_in[4];
    const float* kp_wt    = (const float*)d_in[5];
    float* out = (float*)d_out;

    float* partials = (float*)d_ws;          // [NBLK*2], fully overwritten each call

    fused_loss_kernel<<<NBLK, NTHR, 0, stream>>>(src_flow, trg_flow, src_kp, trg_kp,
                                                 kp_vis, kp_wt, partials);
    finalize_kernel<<<1, 256, 0, stream>>>(partials, out);
}